// Round 5
// baseline (509.468 us; speedup 1.0000x reference)
//
#include <hip/hip_runtime.h>
#include <hip/hip_bf16.h>

// LSTMFeatureExtractor: 2-layer LSTM (H=64, IN=1, B=2048, T=512) + FC(64->32)+ReLU
// R10 = anti-phased co-resident blocks. R9 counters: step pinned at ~1322cy with
// MFMA 417 + VALU 700 + >=205cy both-pipes-idle -> the single block's 8 waves are
// phase-locked by the per-step barrier (cell phases contend VALU, MFMA phases
// contend matrix pipe, barrier realigns). Fix: MB=4, 512 thr, grid 512 ->
// 2 INDEPENDENT blocks per CU (4 waves/SIMD): block A's barrier stalls are
// covered by block B's issue. Cost: 4x M-replication -> 48 MFMA/SIMD/step
// (835cy) but that now overlaps VALU + the other block's stalls.
// Wave structure = R9 (specialized L0/L1, accA prefetch, prescaled weights,
// bias/x folded into MFMA C). 1 cell/lane (batch = quad, acc elem [0]).

#define HID 64
#define TSTEPS 512
#define MB 4
#define RS 80   // f16 row stride: 160B

typedef _Float16 f16x8 __attribute__((ext_vector_type(8)));
typedef float f32x4 __attribute__((ext_vector_type(4)));

#define KSIG (-1.44269504089f)   // -log2(e)
#define KTANH (2.88539008178f)   // 2*log2(e)

__device__ __forceinline__ float sig1(float p) {   // p pre-scaled by KSIG
    return __builtin_amdgcn_rcpf(1.f + __builtin_amdgcn_exp2f(p));
}
__device__ __forceinline__ float th1(float p) {    // p pre-scaled by KTANH
    return 1.f - 2.f * __builtin_amdgcn_rcpf(1.f + __builtin_amdgcn_exp2f(p));
}

__global__ __launch_bounds__(512, 4) void lstm_feat_kernel(
    const float* __restrict__ x,
    const float* __restrict__ Wih0, const float* __restrict__ Whh0,
    const float* __restrict__ bih0, const float* __restrict__ bhh0,
    const float* __restrict__ Wih1, const float* __restrict__ Whh1,
    const float* __restrict__ bih1, const float* __restrict__ bhh1,
    const float* __restrict__ fcW, const float* __restrict__ fcb,
    float* __restrict__ out)
{
    __shared__ __align__(16) float x_lds[MB * TSTEPS];      // [b][t], 8 KB
    __shared__ __align__(16) _Float16 h0_lds[4][MB * RS];   // H0[t] in buf t&3
    __shared__ __align__(16) _Float16 h1_lds[2][MB * RS];   // H1[s] in buf s&1
    __shared__ float h1f32[MB * HID];
    __shared__ float fcw_lds[HID * 32];                     // transposed [k][o]
    __shared__ float fcb_lds[32];

    const int tid  = threadIdx.x;
    const int wave = tid >> 6;
    const int lane = tid & 63;
    const int nq   = lane & 15;
    const int quad = lane >> 4;
    const int bbase = blockIdx.x * MB;
    const bool isL1 = (wave >= 4);     // waves 0-3: layer0, waves 4-7: layer1
    const int ug = wave & 3;
    const int u  = ug * 16 + nq;       // hidden unit owned by this lane

    // ---- one-time staging ----
    for (int i = tid; i < MB * TSTEPS; i += 512) {
        int r = i >> 9, t = i & (TSTEPS - 1);
        x_lds[r * TSTEPS + t] = x[(bbase + r) * TSTEPS + t];   // coalesced in t
    }
    for (int i = tid; i < 32 * HID; i += 512) {
        int o = i >> 6, kk = i & 63;
        fcw_lds[kk * 32 + o] = fcW[i];
    }
    if (tid < 32) fcb_lds[tid] = fcb[tid];
    for (int i = tid; i < 4 * MB * RS; i += 512) ((_Float16*)h0_lds)[i] = (_Float16)0.f;
    for (int i = tid; i < 2 * MB * RS; i += 512) ((_Float16*)h1_lds)[i] = (_Float16)0.f;

    // ---- per-lane weight fragments, PRE-SCALED by gate constant ----
    // L0 waves: wA = Whh0. L1 waves: wA = Wih1, wB = Whh1.
    f16x8 wA[4][2], wB[4][2];
    f32x4 cbias[4];
    float bsc[4], wx0s[4];
    {
        const float* Wa = isL1 ? Wih1 : Whh0;
        const float* Wb = isL1 ? Whh1 : Whh0;
        const float* bi = isL1 ? bih1 : bih0;
        const float* bh = isL1 ? bhh1 : bhh0;
        #pragma unroll
        for (int g = 0; g < 4; ++g) {
            const float sc = (g == 2) ? KTANH : KSIG;
            const int n = g * 64 + u;
            const float bs = (bi[n] + bh[n]) * sc;
            bsc[g] = bs;
            cbias[g] = (f32x4){bs, bs, bs, bs};
            wx0s[g] = Wih0[n] * sc;    // IN==1 (L0 waves only)
            #pragma unroll
            for (int ks = 0; ks < 2; ++ks) {
                const int k0 = quad * 8 + ks * 32;
                f16x8 a, b;
                #pragma unroll
                for (int j = 0; j < 8; ++j) {
                    a[j] = (_Float16)(Wa[n * HID + k0 + j] * sc);
                    b[j] = (_Float16)(Wb[n * HID + k0 + j] * sc);
                }
                wA[g][ks] = a; wB[g][ks] = b;
            }
        }
    }

    // A row m carries h[m>>2] (4x repl); lane's A-row = nq -> batch nq>>2.
    // D rows quad*4+reg all map to batch quad -> element [0] is this lane's cell.
    const int arow = (nq >> 2) * RS + quad * 8;
    float c0 = 0.f;
    f32x4 accA[4] = { {0,0,0,0},{0,0,0,0},{0,0,0,0},{0,0,0,0} };

    __syncthreads();

// ---- single-cell math: pre-act straight from acc elem 0 ----
#define CELL1(AC, DST) do {                                                       \
    float iv = sig1(AC[0][0]);                                                    \
    float fv = sig1(AC[1][0]);                                                    \
    float gv = th1(AC[2][0]);                                                     \
    float ov = sig1(AC[3][0]);                                                    \
    c0 = fv * c0 + iv * gv;                                                       \
    (DST)[quad * RS + u] = (_Float16)(ov * th1(c0 * KTANH));                      \
} while (0)

// ---- L0 interval j: H0[j] (buf P) + x[j] -> H0[j+1] (buf Q) ----
#define L0_STEP(P, Q, XS) do {                                                    \
    f16x8 a0 = *(const f16x8*)&h0_lds[P][arow];                                   \
    f16x8 a1 = *(const f16x8*)&h0_lds[P][arow + 32];                              \
    f32x4 ac[4];                                                                  \
    __builtin_amdgcn_s_setprio(1);                                                \
    _Pragma("unroll")                                                             \
    for (int g = 0; g < 4; ++g) {                                                 \
        const float cv = fmaf((XS), wx0s[g], bsc[g]);                             \
        f32x4 Cg = {cv, cv, cv, cv};                                              \
        ac[g] = __builtin_amdgcn_mfma_f32_16x16x32_f16(a0, wA[g][0], Cg, 0, 0, 0);\
    }                                                                             \
    _Pragma("unroll")                                                             \
    for (int g = 0; g < 4; ++g)                                                   \
        ac[g] = __builtin_amdgcn_mfma_f32_16x16x32_f16(a1, wA[g][1], ac[g], 0, 0, 0); \
    __builtin_amdgcn_s_setprio(0);                                                \
    CELL1(ac, h0_lds[Q]);                                                         \
} while (0)

// ---- L1 interval j (s=j-1): accB over H1[s-1] (h1 buf RB) chained onto
//      prefetched accA; cell -> H1[s] (h1 buf WRB); prefetch accA from
//      H0[j] (h0 buf PF) for interval j+1 ----
#define L1_STEP(RB, WRB, PF) do {                                                 \
    f16x8 b0v = *(const f16x8*)&h1_lds[RB][arow];                                 \
    f16x8 b1v = *(const f16x8*)&h1_lds[RB][arow + 32];                            \
    f16x8 p0 = *(const f16x8*)&h0_lds[PF][arow];                                  \
    f16x8 p1 = *(const f16x8*)&h0_lds[PF][arow + 32];                             \
    f32x4 ac[4];                                                                  \
    __builtin_amdgcn_s_setprio(1);                                                \
    _Pragma("unroll")                                                             \
    for (int g = 0; g < 4; ++g)                                                   \
        ac[g] = __builtin_amdgcn_mfma_f32_16x16x32_f16(b0v, wB[g][0], accA[g], 0, 0, 0); \
    _Pragma("unroll")                                                             \
    for (int g = 0; g < 4; ++g)                                                   \
        ac[g] = __builtin_amdgcn_mfma_f32_16x16x32_f16(b1v, wB[g][1], ac[g], 0, 0, 0);   \
    __builtin_amdgcn_s_setprio(0);                                                \
    _Pragma("unroll")                                                             \
    for (int g = 0; g < 4; ++g)                                                   \
        accA[g] = __builtin_amdgcn_mfma_f32_16x16x32_f16(p0, wA[g][0], cbias[g], 0, 0, 0); \
    _Pragma("unroll")                                                             \
    for (int g = 0; g < 4; ++g)                                                   \
        accA[g] = __builtin_amdgcn_mfma_f32_16x16x32_f16(p1, wA[g][1], accA[g], 0, 0, 0);  \
    CELL1(ac, h1_lds[WRB]);                                                       \
} while (0)

// ---- L1 prefetch-only (prologue intervals) ----
#define L1_PF(PF) do {                                                            \
    f16x8 p0 = *(const f16x8*)&h0_lds[PF][arow];                                  \
    f16x8 p1 = *(const f16x8*)&h0_lds[PF][arow + 32];                             \
    _Pragma("unroll")                                                             \
    for (int g = 0; g < 4; ++g)                                                   \
        accA[g] = __builtin_amdgcn_mfma_f32_16x16x32_f16(p0, wA[g][0], cbias[g], 0, 0, 0); \
    _Pragma("unroll")                                                             \
    for (int g = 0; g < 4; ++g)                                                   \
        accA[g] = __builtin_amdgcn_mfma_f32_16x16x32_f16(p1, wA[g][1], accA[g], 0, 0, 0);  \
} while (0)

    const int xoff = quad * TSTEPS;

    // ---- prologue intervals j=0..3 ----
    {
        const f32x4 xv = *(const f32x4*)&x_lds[xoff];
        if (!isL1) L0_STEP(0, 1, xv[0]); else L1_PF(0);
        __syncthreads();
        if (!isL1) L0_STEP(1, 2, xv[1]); else L1_PF(1);
        __syncthreads();
        if (!isL1) L0_STEP(2, 3, xv[2]); else L1_STEP(0, 1, 2);
        __syncthreads();
        if (!isL1) L0_STEP(3, 0, xv[3]); else L1_STEP(1, 0, 3);
        __syncthreads();
    }

    // ---- main loop: intervals j=k..k+3 ----
    for (int k = 4; k < TSTEPS; k += 4) {
        const f32x4 xv = *(const f32x4*)&x_lds[xoff + k];
        if (!isL1) L0_STEP(0, 1, xv[0]); else L1_STEP(0, 1, 0);
        __syncthreads();
        if (!isL1) L0_STEP(1, 2, xv[1]); else L1_STEP(1, 0, 1);
        __syncthreads();
        if (!isL1) L0_STEP(2, 3, xv[2]); else L1_STEP(0, 1, 2);
        __syncthreads();
        if (!isL1) L0_STEP(3, 0, xv[3]); else L1_STEP(1, 0, 3);
        __syncthreads();
    }

    // ---- peeled s=511: accA holds Wih1*H0[511]+b; state H1[510] in buf 0 ----
    if (isL1) {
        f16x8 b0v = *(const f16x8*)&h1_lds[0][arow];
        f16x8 b1v = *(const f16x8*)&h1_lds[0][arow + 32];
        f32x4 ac[4];
        #pragma unroll
        for (int g = 0; g < 4; ++g)
            ac[g] = __builtin_amdgcn_mfma_f32_16x16x32_f16(b0v, wB[g][0], accA[g], 0, 0, 0);
        #pragma unroll
        for (int g = 0; g < 4; ++g)
            ac[g] = __builtin_amdgcn_mfma_f32_16x16x32_f16(b1v, wB[g][1], ac[g], 0, 0, 0);
        CELL1(ac, h1_lds[1]);
    }
    __syncthreads();

    // ---- peeled s=512: H0[512] in h0 buf 0, H1[511] in h1 buf 1 ----
    if (isL1) {
        f16x8 p0  = *(const f16x8*)&h0_lds[0][arow];
        f16x8 p1  = *(const f16x8*)&h0_lds[0][arow + 32];
        f16x8 b0v = *(const f16x8*)&h1_lds[1][arow];
        f16x8 b1v = *(const f16x8*)&h1_lds[1][arow + 32];
        f32x4 ac[4];
        #pragma unroll
        for (int g = 0; g < 4; ++g)
            ac[g] = __builtin_amdgcn_mfma_f32_16x16x32_f16(p0, wA[g][0], cbias[g], 0, 0, 0);
        #pragma unroll
        for (int g = 0; g < 4; ++g)
            ac[g] = __builtin_amdgcn_mfma_f32_16x16x32_f16(p1, wA[g][1], ac[g], 0, 0, 0);
        #pragma unroll
        for (int g = 0; g < 4; ++g)
            ac[g] = __builtin_amdgcn_mfma_f32_16x16x32_f16(b0v, wB[g][0], ac[g], 0, 0, 0);
        #pragma unroll
        for (int g = 0; g < 4; ++g)
            ac[g] = __builtin_amdgcn_mfma_f32_16x16x32_f16(b1v, wB[g][1], ac[g], 0, 0, 0);
        float iv = sig1(ac[0][0]);
        float fv = sig1(ac[1][0]);
        float gv = th1(ac[2][0]);
        float ov = sig1(ac[3][0]);
        c0 = fv * c0 + iv * gv;
        h1f32[quad * HID + u] = ov * th1(c0 * KTANH);
    }
    __syncthreads();

    // ---- epilogue: features = relu(H1[512] @ fcW^T + fcb) ----
    if (tid < MB * 32) {
        const int o  = tid & 31;
        const int rr = tid >> 5;
        float acc = fcb_lds[o];
        #pragma unroll 8
        for (int kk = 0; kk < HID; ++kk)
            acc += h1f32[rr * HID + kk] * fcw_lds[kk * 32 + o];
        out[(bbase + rr) * 32 + o] = fmaxf(acc, 0.f);
    }
}

extern "C" void kernel_launch(void* const* d_in, const int* in_sizes, int n_in,
                              void* d_out, int out_size, void* d_ws, size_t ws_size,
                              hipStream_t stream) {
    const float* x    = (const float*)d_in[0];
    const float* Wih0 = (const float*)d_in[1];
    const float* Whh0 = (const float*)d_in[2];
    const float* bih0 = (const float*)d_in[3];
    const float* bhh0 = (const float*)d_in[4];
    const float* Wih1 = (const float*)d_in[5];
    const float* Whh1 = (const float*)d_in[6];
    const float* bih1 = (const float*)d_in[7];
    const float* bhh1 = (const float*)d_in[8];
    const float* fcW  = (const float*)d_in[9];
    const float* fcb  = (const float*)d_in[10];
    float* out = (float*)d_out;

    lstm_feat_kernel<<<2048 / MB, 512, 0, stream>>>(
        x, Wih0, Whh0, bih0, bhh0, Wih1, Whh1, bih1, bhh1, fcW, fcb, out);
}

// Round 6
// 435.416 us; speedup vs baseline: 1.1701x; 1.1701x over previous
//
#include <hip/hip_runtime.h>
#include <hip/hip_bf16.h>

// LSTMFeatureExtractor: 2-layer LSTM (H=64, IN=1, B=2048, T=512) + FC(64->32)+ReLU
// R11 = replace the per-step __syncthreads with a producer-consumer flag
// protocol. R10 failed on VGPR spills (WRITE_SIZE 62MB) -- not a theory test.
// R8/R9 evidence stands: 2 waves/SIMD phase-locked by the barrier run MFMA
// (417cy) and VALU (646cy) serially. Dataflow: L1 never feeds L0; only
// (a) L1 step k needs H0[k], (b) L0 can't clobber H0[j-3] pre-consumption.
// So: H0 = 4-deep ring, per-wave LDS progress counters, spin-wait (s_sleep)
// on exactly the needed minima; L0 free-runs up to 3 steps ahead; the L0/L1
// waves sharing a SIMD drift -> trans chains overlap MFMA bursts.
// L0 waits: min(cnt0)>=j-1 && min(cnt1)>=j-3. L1 waits: both >= k-1.
// Deadlock-free: blocked-L0 => some L1 at k<=J-3; blocked-L1 => k>J. Contra.
// L1 full 4-chain MFMA (bias in first C) kills the pre-act adds.

#define HID 64
#define TSTEPS 512
#define MB 8
#define RS 80   // f16 row stride: 160B

typedef _Float16 f16x8 __attribute__((ext_vector_type(8)));
typedef float f32x4 __attribute__((ext_vector_type(4)));

#define KSIG (-1.44269504089f)   // -log2(e)
#define KTANH (2.88539008178f)   // 2*log2(e)

__device__ __forceinline__ float sig1(float p) {   // p pre-scaled by KSIG
    return __builtin_amdgcn_rcpf(1.f + __builtin_amdgcn_exp2f(p));
}
__device__ __forceinline__ float th1(float p) {    // p pre-scaled by KTANH
    return 1.f - 2.f * __builtin_amdgcn_rcpf(1.f + __builtin_amdgcn_exp2f(p));
}
__device__ __forceinline__ int imin(int a, int b) { return a < b ? a : b; }

__global__ __launch_bounds__(512, 1) void lstm_feat_kernel(
    const float* __restrict__ x,
    const float* __restrict__ Wih0, const float* __restrict__ Whh0,
    const float* __restrict__ bih0, const float* __restrict__ bhh0,
    const float* __restrict__ Wih1, const float* __restrict__ Whh1,
    const float* __restrict__ bih1, const float* __restrict__ bhh1,
    const float* __restrict__ fcW, const float* __restrict__ fcb,
    float* __restrict__ out)
{
    __shared__ __align__(16) float x_lds[(MB / 2) * TSTEPS * 2]; // [qp][t][2]
    __shared__ __align__(16) _Float16 h0_lds[4][MB * RS];        // H0[t] ring, slot t&3
    __shared__ __align__(16) _Float16 h1_lds[2][MB * RS];        // H1[s], slot s&1
    __shared__ float h1f32[MB * HID];
    __shared__ float fcw_lds[HID * 32];                          // transposed [k][o]
    __shared__ float fcb_lds[32];
    __shared__ int cnt[8];   // [0..3]=L0 wave progress, [4..7]=L1 wave progress

    const int tid  = threadIdx.x;
    const int wave = tid >> 6;
    const int lane = tid & 63;
    const int nq   = lane & 15;
    const int quad = lane >> 4;
    const int bbase = blockIdx.x * MB;
    const bool isL1 = (wave >= 4);     // waves 0-3: layer0, waves 4-7: layer1
    const int ug = wave & 3;
    const int u  = ug * 16 + nq;       // hidden unit owned by this lane

    // ---- one-time staging ----
    for (int i = tid; i < TSTEPS * MB; i += 512) {
        int r = i >> 9, t = i & (TSTEPS - 1);
        x_lds[(r >> 1) * (TSTEPS * 2) + t * 2 + (r & 1)] = x[(bbase + r) * TSTEPS + t];
    }
    for (int i = tid; i < 32 * HID; i += 512) {
        int o = i >> 6, kk = i & 63;
        fcw_lds[kk * 32 + o] = fcW[i];
    }
    if (tid < 32) fcb_lds[tid] = fcb[tid];
    for (int i = tid; i < 4 * MB * RS; i += 512) ((_Float16*)h0_lds)[i] = (_Float16)0.f;
    for (int i = tid; i < 2 * MB * RS; i += 512) ((_Float16*)h1_lds)[i] = (_Float16)0.f;
    if (tid < 4) cnt[tid] = -1;            // L0: no step done
    else if (tid < 8) cnt[tid] = 0;        // L1: "step 0" done (H1[0]=0 pre-zeroed)

    // ---- per-lane weight fragments, PRE-SCALED by gate constant ----
    // L0 waves: wA = Whh0. L1 waves: wA = Wih1, wB = Whh1.
    f16x8 wA[4][2], wB[4][2];
    f32x4 cbias[4];
    float wx0s[4];
    {
        const float* Wa = isL1 ? Wih1 : Whh0;
        const float* bi = isL1 ? bih1 : bih0;
        const float* bh = isL1 ? bhh1 : bhh0;
        #pragma unroll
        for (int g = 0; g < 4; ++g) {
            const float sc = (g == 2) ? KTANH : KSIG;
            const int n = g * 64 + u;
            const float bs = (bi[n] + bh[n]) * sc;
            cbias[g] = (f32x4){bs, bs, bs, bs};
            wx0s[g] = Wih0[n] * sc;    // IN==1 (L0 waves only)
            #pragma unroll
            for (int ks = 0; ks < 2; ++ks) {
                const int k0 = quad * 8 + ks * 32;
                f16x8 a;
                #pragma unroll
                for (int j = 0; j < 8; ++j)
                    a[j] = (_Float16)(Wa[n * HID + k0 + j] * sc);
                wA[g][ks] = a;
            }
        }
        if (isL1) {
            #pragma unroll
            for (int g = 0; g < 4; ++g) {
                const float sc = (g == 2) ? KTANH : KSIG;
                const int n = g * 64 + u;
                #pragma unroll
                for (int ks = 0; ks < 2; ++ks) {
                    const int k0 = quad * 8 + ks * 32;
                    f16x8 b;
                    #pragma unroll
                    for (int j = 0; j < 8; ++j)
                        b[j] = (_Float16)(Whh1[n * HID + k0 + j] * sc);
                    wB[g][ks] = b;
                }
            }
        }
    }

    // A row m carries h[m>>1]; D rows quad*4+{0,1}->batch b0 (elem 0),
    // {2,3}->b0+1 (elem 2).
    const int arow = (nq >> 1) * RS + quad * 8;
    const int b0r  = (quad * 2) * RS;
    const int hbase = quad * 2;
    float c0 = 0.f, c1 = 0.f;

    __syncthreads();

// ---- spin until L0-group min >= N0 and L1-group min >= N1 ----
#define SPIN(N0, N1) do {                                                        \
    volatile int* cv = cnt;                                                      \
    for (;;) {                                                                   \
        int m0 = imin(imin(cv[0], cv[1]), imin(cv[2], cv[3]));                   \
        int m1 = imin(imin(cv[4], cv[5]), imin(cv[6], cv[7]));                   \
        if (m0 >= (N0) && m1 >= (N1)) break;                                     \
        __builtin_amdgcn_s_sleep(1);                                             \
    }                                                                            \
    asm volatile("" ::: "memory");                                               \
} while (0)

// ---- drain our LDS writes, then publish progress ----
#define PUBLISH(V) do {                                                          \
    __threadfence_block();                                                       \
    if (lane == 0) ((volatile int*)cnt)[wave] = (V);                             \
} while (0)

// ---- L0 step J: H0[J+1] = cell(H0[J] (slot P), x[J]); write slot Q ----
#define L0_ONE(J, P, Q, XA, XB) do {                                             \
    SPIN((J) - 1, (J) - 3);                                                      \
    f16x8 a0 = *(const f16x8*)&h0_lds[P][arow];                                  \
    f16x8 a1 = *(const f16x8*)&h0_lds[P][arow + 32];                             \
    f32x4 ac[4];                                                                 \
    __builtin_amdgcn_s_setprio(1);                                               \
    _Pragma("unroll")                                                            \
    for (int g = 0; g < 4; ++g)                                                  \
        ac[g] = __builtin_amdgcn_mfma_f32_16x16x32_f16(a0, wA[g][0], cbias[g], 0, 0, 0); \
    _Pragma("unroll")                                                            \
    for (int g = 0; g < 4; ++g)                                                  \
        ac[g] = __builtin_amdgcn_mfma_f32_16x16x32_f16(a1, wA[g][1], ac[g], 0, 0, 0);    \
    __builtin_amdgcn_s_setprio(0);                                               \
    float pi0 = fmaf((XA), wx0s[0], ac[0][0]), pi1 = fmaf((XB), wx0s[0], ac[0][2]); \
    float pf0 = fmaf((XA), wx0s[1], ac[1][0]), pf1 = fmaf((XB), wx0s[1], ac[1][2]); \
    float pg0 = fmaf((XA), wx0s[2], ac[2][0]), pg1 = fmaf((XB), wx0s[2], ac[2][2]); \
    float po0 = fmaf((XA), wx0s[3], ac[3][0]), po1 = fmaf((XB), wx0s[3], ac[3][2]); \
    float iv0 = sig1(pi0), iv1 = sig1(pi1);                                      \
    float fv0 = sig1(pf0), fv1 = sig1(pf1);                                      \
    float gv0 = th1(pg0),  gv1 = th1(pg1);                                       \
    float ov0 = sig1(po0), ov1 = sig1(po1);                                      \
    c0 = fmaf(fv0, c0, iv0 * gv0);  c1 = fmaf(fv1, c1, iv1 * gv1);               \
    h0_lds[Q][b0r + u]      = (_Float16)(ov0 * th1(c0 * KTANH));                 \
    h0_lds[Q][b0r + RS + u] = (_Float16)(ov1 * th1(c1 * KTANH));                 \
    PUBLISH(J);                                                                  \
} while (0)

// ---- L1 step K: H1[K] = cell(H1[K-1] (slot RB), H0[K] (slot PH)); write WB ----
#define L1_ONE(K, PH, RB, WB) do {                                               \
    SPIN((K) - 1, (K) - 1);                                                      \
    f16x8 a00 = *(const f16x8*)&h0_lds[PH][arow];                                \
    f16x8 a01 = *(const f16x8*)&h0_lds[PH][arow + 32];                           \
    f16x8 a10 = *(const f16x8*)&h1_lds[RB][arow];                                \
    f16x8 a11 = *(const f16x8*)&h1_lds[RB][arow + 32];                           \
    f32x4 ac[4];                                                                 \
    __builtin_amdgcn_s_setprio(1);                                               \
    _Pragma("unroll")                                                            \
    for (int g = 0; g < 4; ++g)                                                  \
        ac[g] = __builtin_amdgcn_mfma_f32_16x16x32_f16(a00, wA[g][0], cbias[g], 0, 0, 0); \
    _Pragma("unroll")                                                            \
    for (int g = 0; g < 4; ++g)                                                  \
        ac[g] = __builtin_amdgcn_mfma_f32_16x16x32_f16(a01, wA[g][1], ac[g], 0, 0, 0);   \
    _Pragma("unroll")                                                            \
    for (int g = 0; g < 4; ++g)                                                  \
        ac[g] = __builtin_amdgcn_mfma_f32_16x16x32_f16(a10, wB[g][0], ac[g], 0, 0, 0);   \
    _Pragma("unroll")                                                            \
    for (int g = 0; g < 4; ++g)                                                  \
        ac[g] = __builtin_amdgcn_mfma_f32_16x16x32_f16(a11, wB[g][1], ac[g], 0, 0, 0);   \
    __builtin_amdgcn_s_setprio(0);                                               \
    float iv0 = sig1(ac[0][0]), iv1 = sig1(ac[0][2]);                            \
    float fv0 = sig1(ac[1][0]), fv1 = sig1(ac[1][2]);                            \
    float gv0 = th1(ac[2][0]),  gv1 = th1(ac[2][2]);                             \
    float ov0 = sig1(ac[3][0]), ov1 = sig1(ac[3][2]);                            \
    c0 = fmaf(fv0, c0, iv0 * gv0);  c1 = fmaf(fv1, c1, iv1 * gv1);               \
    h1_lds[WB][b0r + u]      = (_Float16)(ov0 * th1(c0 * KTANH));                \
    h1_lds[WB][b0r + RS + u] = (_Float16)(ov1 * th1(c1 * KTANH));                \
    PUBLISH(K);                                                                  \
} while (0)

    const int xoff = quad * (TSTEPS * 2);

    if (!isL1) {
        // ---- L0: steps j = 0..511, ring slots j&3 -> (j+1)&3 ----
        for (int j4 = 0; j4 < TSTEPS; j4 += 4) {
            const f32x4 xva = *(const f32x4*)&x_lds[xoff + j4 * 2];
            const f32x4 xvb = *(const f32x4*)&x_lds[xoff + j4 * 2 + 4];
            L0_ONE(j4 + 0, 0, 1, xva[0], xva[1]);
            L0_ONE(j4 + 1, 1, 2, xva[2], xva[3]);
            L0_ONE(j4 + 2, 2, 3, xvb[0], xvb[1]);
            L0_ONE(j4 + 3, 3, 0, xvb[2], xvb[3]);
        }
    } else {
        // ---- L1: steps k = 1..508 unrolled (slots: h0 k&3, h1 (k-1)&1 -> k&1) ----
        for (int k4 = 1; k4 <= TSTEPS - 7; k4 += 4) {
            L1_ONE(k4 + 0, 1, 0, 1);
            L1_ONE(k4 + 1, 2, 1, 0);
            L1_ONE(k4 + 2, 3, 0, 1);
            L1_ONE(k4 + 3, 0, 1, 0);
        }
        // k = 509, 510, 511 still to LDS
        L1_ONE(509, 1, 0, 1);
        L1_ONE(510, 2, 1, 0);
        L1_ONE(511, 3, 0, 1);
        // ---- k = 512: H0[512] in slot 0, H1[511] in slot 1 -> h1f32 ----
        {
            SPIN(511, 511);
            f16x8 a00 = *(const f16x8*)&h0_lds[0][arow];
            f16x8 a01 = *(const f16x8*)&h0_lds[0][arow + 32];
            f16x8 a10 = *(const f16x8*)&h1_lds[1][arow];
            f16x8 a11 = *(const f16x8*)&h1_lds[1][arow + 32];
            f32x4 ac[4];
            #pragma unroll
            for (int g = 0; g < 4; ++g)
                ac[g] = __builtin_amdgcn_mfma_f32_16x16x32_f16(a00, wA[g][0], cbias[g], 0, 0, 0);
            #pragma unroll
            for (int g = 0; g < 4; ++g)
                ac[g] = __builtin_amdgcn_mfma_f32_16x16x32_f16(a01, wA[g][1], ac[g], 0, 0, 0);
            #pragma unroll
            for (int g = 0; g < 4; ++g)
                ac[g] = __builtin_amdgcn_mfma_f32_16x16x32_f16(a10, wB[g][0], ac[g], 0, 0, 0);
            #pragma unroll
            for (int g = 0; g < 4; ++g)
                ac[g] = __builtin_amdgcn_mfma_f32_16x16x32_f16(a11, wB[g][1], ac[g], 0, 0, 0);
            float iv0 = sig1(ac[0][0]), iv1 = sig1(ac[0][2]);
            float fv0 = sig1(ac[1][0]), fv1 = sig1(ac[1][2]);
            float gv0 = th1(ac[2][0]),  gv1 = th1(ac[2][2]);
            float ov0 = sig1(ac[3][0]), ov1 = sig1(ac[3][2]);
            c0 = fmaf(fv0, c0, iv0 * gv0);  c1 = fmaf(fv1, c1, iv1 * gv1);
            h1f32[hbase * HID + u]       = ov0 * th1(c0 * KTANH);
            h1f32[(hbase + 1) * HID + u] = ov1 * th1(c1 * KTANH);
        }
    }
    __syncthreads();

    // ---- epilogue: features = relu(H1[512] @ fcW^T + fcb) ----
    if (tid < MB * 32) {
        const int o  = tid & 31;
        const int rr = tid >> 5;
        float acc = fcb_lds[o];
        #pragma unroll 8
        for (int kk = 0; kk < HID; ++kk)
            acc += h1f32[rr * HID + kk] * fcw_lds[kk * 32 + o];
        out[(bbase + rr) * 32 + o] = fmaxf(acc, 0.f);
    }
}

extern "C" void kernel_launch(void* const* d_in, const int* in_sizes, int n_in,
                              void* d_out, int out_size, void* d_ws, size_t ws_size,
                              hipStream_t stream) {
    const float* x    = (const float*)d_in[0];
    const float* Wih0 = (const float*)d_in[1];
    const float* Whh0 = (const float*)d_in[2];
    const float* bih0 = (const float*)d_in[3];
    const float* bhh0 = (const float*)d_in[4];
    const float* Wih1 = (const float*)d_in[5];
    const float* Whh1 = (const float*)d_in[6];
    const float* bih1 = (const float*)d_in[7];
    const float* bhh1 = (const float*)d_in[8];
    const float* fcW  = (const float*)d_in[9];
    const float* fcb  = (const float*)d_in[10];
    float* out = (float*)d_out;

    lstm_feat_kernel<<<2048 / MB, 512, 0, stream>>>(
        x, Wih0, Whh0, bih0, bhh0, Wih1, Whh1, bih1, bhh1, fcW, fcb, out);
}

// Round 7
// 337.792 us; speedup vs baseline: 1.5082x; 1.2890x over previous
//
#include <hip/hip_runtime.h>
#include <hip/hip_bf16.h>

// LSTMFeatureExtractor: 2-layer LSTM (H=64, IN=1, B=2048, T=512) + FC(64->32)+ReLU
// R12 = anti-phase via mid-step barrier. R11's flag protocol regressed (410us:
// s_sleep quanta + fence drains + 4-chain on the serial path). R6-R9 all show
// the same signature: two waves/SIMD phase-aligned -> MFMA(418cy) and
// VALU(646cy) serialize into a 1331cy step. Fix with the cheap primitive:
// each step = 2 barriered phases, groups swapped:
//   A: L0 read+MFMA (regs)        || L1 cell(n-2) from regs + write H1
//   B: L0 cell + write H0[n+1]    || L1 read H0[n-1],H1[n-2] + 16 MFMA (regs)
// On every SIMD one wave MFMA-issues while the other VALU-issues, enforced
// by hardware barrier. H0 = 4-slot ring, H1 = 2-slot ring; compile-time
// slots; 4 prologue + 2.5 epilogue intervals peeled. L1 pre-act adds folded
// into the MFMA chain (bias in C of first link; 4 independent 4-chains).

#define HID 64
#define TSTEPS 512
#define MB 8
#define RS 80   // f16 row stride: 160B

typedef _Float16 f16x8 __attribute__((ext_vector_type(8)));
typedef float f32x4 __attribute__((ext_vector_type(4)));

#define KSIG (-1.44269504089f)   // -log2(e)
#define KTANH (2.88539008178f)   // 2*log2(e)

__device__ __forceinline__ float sig1(float p) {   // p pre-scaled by KSIG
    return __builtin_amdgcn_rcpf(1.f + __builtin_amdgcn_exp2f(p));
}
__device__ __forceinline__ float th1(float p) {    // p pre-scaled by KTANH
    return 1.f - 2.f * __builtin_amdgcn_rcpf(1.f + __builtin_amdgcn_exp2f(p));
}

#define MFMA16(A, B, C) __builtin_amdgcn_mfma_f32_16x16x32_f16((A), (B), (C), 0, 0, 0)

__global__ __launch_bounds__(512, 1) void lstm_feat_kernel(
    const float* __restrict__ x,
    const float* __restrict__ Wih0, const float* __restrict__ Whh0,
    const float* __restrict__ bih0, const float* __restrict__ bhh0,
    const float* __restrict__ Wih1, const float* __restrict__ Whh1,
    const float* __restrict__ bih1, const float* __restrict__ bhh1,
    const float* __restrict__ fcW, const float* __restrict__ fcb,
    float* __restrict__ out)
{
    __shared__ __align__(16) float x_lds[(MB / 2) * TSTEPS * 2]; // [qp][t][2], 16 KB
    __shared__ __align__(16) _Float16 h0_lds[4][MB * RS];        // H0[t] ring, slot t&3
    __shared__ __align__(16) _Float16 h1_lds[2][MB * RS];        // H1[s] ring, slot s&1
    __shared__ float h1f32[MB * HID];
    __shared__ float fcw_lds[HID * 32];                          // transposed [k][o]
    __shared__ float fcb_lds[32];

    const int tid  = threadIdx.x;
    const int wave = tid >> 6;
    const int lane = tid & 63;
    const int nq   = lane & 15;
    const int quad = lane >> 4;
    const int bbase = blockIdx.x * MB;
    const bool isL1 = (wave >= 4);     // waves 0-3: layer0, waves 4-7: layer1
    const int ug = wave & 3;
    const int u  = ug * 16 + nq;       // hidden unit owned by this lane

    // ---- one-time staging ----
    for (int i = tid; i < TSTEPS * MB; i += 512) {
        int r = i >> 9, t = i & (TSTEPS - 1);
        x_lds[(r >> 1) * (TSTEPS * 2) + t * 2 + (r & 1)] = x[(bbase + r) * TSTEPS + t];
    }
    for (int i = tid; i < 32 * HID; i += 512) {
        int o = i >> 6, kk = i & 63;
        fcw_lds[kk * 32 + o] = fcW[i];
    }
    if (tid < 32) fcb_lds[tid] = fcb[tid];
    for (int i = tid; i < 4 * MB * RS; i += 512) ((_Float16*)h0_lds)[i] = (_Float16)0.f;
    for (int i = tid; i < 2 * MB * RS; i += 512) ((_Float16*)h1_lds)[i] = (_Float16)0.f;

    // ---- per-lane weight fragments, PRE-SCALED by gate constant ----
    // L0 waves: wA = Whh0 (wB unused). L1 waves: wA = Wih1, wB = Whh1.
    f16x8 wA[4][2], wB[4][2];
    f32x4 cbias[4];
    float wx0s[4];
    {
        const float* Wa = isL1 ? Wih1 : Whh0;
        const float* bi = isL1 ? bih1 : bih0;
        const float* bh = isL1 ? bhh1 : bhh0;
        #pragma unroll
        for (int g = 0; g < 4; ++g) {
            const float sc = (g == 2) ? KTANH : KSIG;
            const int n = g * 64 + u;
            const float bs = (bi[n] + bh[n]) * sc;
            cbias[g] = (f32x4){bs, bs, bs, bs};
            wx0s[g] = Wih0[n] * sc;    // IN==1 (L0 waves only)
            #pragma unroll
            for (int ks = 0; ks < 2; ++ks) {
                const int k0 = quad * 8 + ks * 32;
                f16x8 a;
                #pragma unroll
                for (int j = 0; j < 8; ++j)
                    a[j] = (_Float16)(Wa[n * HID + k0 + j] * sc);
                wA[g][ks] = a;
            }
        }
        if (isL1) {
            #pragma unroll
            for (int g = 0; g < 4; ++g) {
                const float sc = (g == 2) ? KTANH : KSIG;
                const int n = g * 64 + u;
                #pragma unroll
                for (int ks = 0; ks < 2; ++ks) {
                    const int k0 = quad * 8 + ks * 32;
                    f16x8 b;
                    #pragma unroll
                    for (int j = 0; j < 8; ++j)
                        b[j] = (_Float16)(Whh1[n * HID + k0 + j] * sc);
                    wB[g][ks] = b;
                }
            }
        }
    }

    // A row m carries h[m>>1]; D rows quad*4+{0,1}->batch b0 (elem 0),
    // {2,3}->b0+1 (elem 2).
    const int arow = (nq >> 1) * RS + quad * 8;
    const int b0r  = (quad * 2) * RS;
    const int hbase = quad * 2;
    float c0 = 0.f, c1 = 0.f;
    f32x4 l0ac[4], l1ac[4];

    __syncthreads();

// ---- L0 phase A: read H0[n] (slot S) + 8 MFMA -> l0ac ----
#define L0A(S) do {                                                               \
    f16x8 a0 = *(const f16x8*)&h0_lds[S][arow];                                   \
    f16x8 a1 = *(const f16x8*)&h0_lds[S][arow + 32];                              \
    __builtin_amdgcn_s_setprio(1);                                                \
    _Pragma("unroll")                                                             \
    for (int g = 0; g < 4; ++g) l0ac[g] = MFMA16(a0, wA[g][0], cbias[g]);         \
    _Pragma("unroll")                                                             \
    for (int g = 0; g < 4; ++g) l0ac[g] = MFMA16(a1, wA[g][1], l0ac[g]);          \
    __builtin_amdgcn_s_setprio(0);                                                \
} while (0)

// ---- L0 phase B: cell from l0ac (+x terms), write H0[n+1] (slot Q) ----
#define L0B(Q, XA, XB) do {                                                       \
    float pi0 = fmaf((XA), wx0s[0], l0ac[0][0]), pi1 = fmaf((XB), wx0s[0], l0ac[0][2]); \
    float pf0 = fmaf((XA), wx0s[1], l0ac[1][0]), pf1 = fmaf((XB), wx0s[1], l0ac[1][2]); \
    float pg0 = fmaf((XA), wx0s[2], l0ac[2][0]), pg1 = fmaf((XB), wx0s[2], l0ac[2][2]); \
    float po0 = fmaf((XA), wx0s[3], l0ac[3][0]), po1 = fmaf((XB), wx0s[3], l0ac[3][2]); \
    float iv0 = sig1(pi0), iv1 = sig1(pi1), fv0 = sig1(pf0), fv1 = sig1(pf1);     \
    float gv0 = th1(pg0),  gv1 = th1(pg1),  ov0 = sig1(po0), ov1 = sig1(po1);     \
    c0 = fmaf(fv0, c0, iv0 * gv0);  c1 = fmaf(fv1, c1, iv1 * gv1);                \
    h0_lds[Q][b0r + u]      = (_Float16)(ov0 * th1(c0 * KTANH));                  \
    h0_lds[Q][b0r + RS + u] = (_Float16)(ov1 * th1(c1 * KTANH));                  \
} while (0)

// ---- L1 phase A: cell from l1ac, write H1[n-2] (slot H1S) ----
#define L1A(H1S) do {                                                             \
    float iv0 = sig1(l1ac[0][0]), iv1 = sig1(l1ac[0][2]);                         \
    float fv0 = sig1(l1ac[1][0]), fv1 = sig1(l1ac[1][2]);                         \
    float gv0 = th1(l1ac[2][0]),  gv1 = th1(l1ac[2][2]);                          \
    float ov0 = sig1(l1ac[3][0]), ov1 = sig1(l1ac[3][2]);                         \
    c0 = fmaf(fv0, c0, iv0 * gv0);  c1 = fmaf(fv1, c1, iv1 * gv1);                \
    h1_lds[H1S][b0r + u]      = (_Float16)(ov0 * th1(c0 * KTANH));                \
    h1_lds[H1S][b0r + RS + u] = (_Float16)(ov1 * th1(c1 * KTANH));                \
} while (0)

// ---- L1 phase B: read H0[n-1] (slot SH0) + H1[n-2] (slot H1S), 16 MFMA ----
#define L1B(SH0, H1S) do {                                                        \
    f16x8 a00 = *(const f16x8*)&h0_lds[SH0][arow];                                \
    f16x8 a01 = *(const f16x8*)&h0_lds[SH0][arow + 32];                           \
    f16x8 a10 = *(const f16x8*)&h1_lds[H1S][arow];                                \
    f16x8 a11 = *(const f16x8*)&h1_lds[H1S][arow + 32];                           \
    __builtin_amdgcn_s_setprio(1);                                                \
    _Pragma("unroll")                                                             \
    for (int g = 0; g < 4; ++g) l1ac[g] = MFMA16(a00, wA[g][0], cbias[g]);        \
    _Pragma("unroll")                                                             \
    for (int g = 0; g < 4; ++g) l1ac[g] = MFMA16(a01, wA[g][1], l1ac[g]);         \
    _Pragma("unroll")                                                             \
    for (int g = 0; g < 4; ++g) l1ac[g] = MFMA16(a10, wB[g][0], l1ac[g]);         \
    _Pragma("unroll")                                                             \
    for (int g = 0; g < 4; ++g) l1ac[g] = MFMA16(a11, wB[g][1], l1ac[g]);         \
    __builtin_amdgcn_s_setprio(0);                                                \
} while (0)

// ---- one interval n: S = n&3, H1S = n&1; DOA/DOB gate L1 work (prologue) ----
#define IV(S, H1S, XA, XB, DOA, DOB) do {                                         \
    if (!isL1) { L0A(S); } else if (DOA) { L1A(H1S); }                            \
    __syncthreads();                                                              \
    if (!isL1) { L0B((S + 1) & 3, XA, XB); } else if (DOB) { L1B((S + 3) & 3, H1S); } \
    __syncthreads();                                                              \
} while (0)

    const int xoff = quad * (TSTEPS * 2);

    // ---- prologue intervals n=0..3 ----
    {
        const f32x4 xv0 = *(const f32x4*)&x_lds[xoff + 0];   // steps 0,1
        const f32x4 xv1 = *(const f32x4*)&x_lds[xoff + 4];   // steps 2,3
        IV(0, 0, xv0[0], xv0[1], false, false);   // n=0
        IV(1, 1, xv0[2], xv0[3], false, false);   // n=1
        IV(2, 0, xv1[0], xv1[1], false, true);    // n=2: first L1 MFMA (k=1)
        IV(3, 1, xv1[2], xv1[3], true,  true);    // n=3: first L1 cell (k=1)
    }

    // ---- main loop: intervals n=4..511, fully active ----
    for (int n = 4; n < TSTEPS; n += 4) {
        const f32x4 xv0 = *(const f32x4*)&x_lds[xoff + n * 2];
        const f32x4 xv1 = *(const f32x4*)&x_lds[xoff + n * 2 + 4];
        IV(0, 0, xv0[0], xv0[1], true, true);
        IV(1, 1, xv0[2], xv0[3], true, true);
        IV(2, 0, xv1[0], xv1[1], true, true);
        IV(3, 1, xv1[2], xv1[3], true, true);
    }

    // ---- epilogue intervals n=512, 513 (L0 idle, barriers shared) ----
    if (isL1) L1A(0);            // cell k=510 -> H1[510] slot 0
    __syncthreads();
    if (isL1) L1B(3, 0);         // MFMA k=511: H0[511] slot 3, H1[510] slot 0
    __syncthreads();
    if (isL1) L1A(1);            // cell k=511 -> H1[511] slot 1
    __syncthreads();
    if (isL1) L1B(0, 1);         // MFMA k=512: H0[512] slot 0, H1[511] slot 1
    __syncthreads();

    // ---- final cell k=512 -> h1f32 ----
    if (isL1) {
        float iv0 = sig1(l1ac[0][0]), iv1 = sig1(l1ac[0][2]);
        float fv0 = sig1(l1ac[1][0]), fv1 = sig1(l1ac[1][2]);
        float gv0 = th1(l1ac[2][0]),  gv1 = th1(l1ac[2][2]);
        float ov0 = sig1(l1ac[3][0]), ov1 = sig1(l1ac[3][2]);
        c0 = fmaf(fv0, c0, iv0 * gv0);  c1 = fmaf(fv1, c1, iv1 * gv1);
        h1f32[hbase * HID + u]       = ov0 * th1(c0 * KTANH);
        h1f32[(hbase + 1) * HID + u] = ov1 * th1(c1 * KTANH);
    }
    __syncthreads();

    // ---- epilogue: features = relu(H1[512] @ fcW^T + fcb) ----
    if (tid < MB * 32) {
        const int o  = tid & 31;
        const int rr = tid >> 5;
        float acc = fcb_lds[o];
        #pragma unroll 8
        for (int kk = 0; kk < HID; ++kk)
            acc += h1f32[rr * HID + kk] * fcw_lds[kk * 32 + o];
        out[(bbase + rr) * 32 + o] = fmaxf(acc, 0.f);
    }
}

extern "C" void kernel_launch(void* const* d_in, const int* in_sizes, int n_in,
                              void* d_out, int out_size, void* d_ws, size_t ws_size,
                              hipStream_t stream) {
    const float* x    = (const float*)d_in[0];
    const float* Wih0 = (const float*)d_in[1];
    const float* Whh0 = (const float*)d_in[2];
    const float* bih0 = (const float*)d_in[3];
    const float* bhh0 = (const float*)d_in[4];
    const float* Wih1 = (const float*)d_in[5];
    const float* Whh1 = (const float*)d_in[6];
    const float* bih1 = (const float*)d_in[7];
    const float* bhh1 = (const float*)d_in[8];
    const float* fcW  = (const float*)d_in[9];
    const float* fcb  = (const float*)d_in[10];
    float* out = (float*)d_out;

    lstm_feat_kernel<<<2048 / MB, 512, 0, stream>>>(
        x, Wih0, Whh0, bih0, bhh0, Wih1, Whh1, bih1, bhh1, fcW, fcb, out);
}